// Round 13
// baseline (207.734 us; speedup 1.0000x reference)
//
#include <hip/hip_runtime.h>

// NonLocalBlock B=8, L=2048, C=512, CI=256 (fp32 in/out).
// Round 19 (= round 18 with the crash bug fixed):
//   - BUG FIX: score epilogue plane pitch 68 -> 72. 68 % 8 != 0 made odd
//     rows' uint4 (ds_read_b128) plane reads only 8B-aligned -> misaligned
//     b128 LDS access -> memory violation -> dead container (r18 failure).
//     Pitch 72 is 16B-aligned for all rows; phase-3 scalar writes stay
//     2-lanes/bank (free); SM 36864 u16 = 72 KB, still 2 blocks/CU.
//   - cvt_x ELIMINATED (proj stages A from X fp32 with in-reg convert +
//     ds_write_b128 to the identical LDS slot; swizzle invariant preserved).
//   - score epilogue: regs -> softmax -> per-batch planes -> uint4 ATT write.
//   - score GEMM + r17 XCD patch swizzle; out r16 + r13 swizzle unchanged.
//   All-fp16, XOR k-chunk swizzle.

#define NB 8
#define NL 2048
#define NC 512
#define NCI 256

using f16x8 = __attribute__((ext_vector_type(8))) _Float16;
using f32x4 = __attribute__((ext_vector_type(4))) float;
typedef unsigned short u16;

__device__ __forceinline__ u16 f16b(float x) {
    _Float16 h = (_Float16)x;
    return __builtin_bit_cast(u16, h);
}
__device__ __forceinline__ float f16tof(u16 u) {
    return (float)__builtin_bit_cast(_Float16, u);
}
__device__ __forceinline__ void gload16(const void* g, void* l) {
    __builtin_amdgcn_global_load_lds((__attribute__((address_space(1))) void*)g,
                                     (__attribute__((address_space(3))) void*)l,
                                     16, 0, 0);
}

// ---- cvt: transpose weights to [n][k] fp16 --------------------------------
__global__ __launch_bounds__(256) void cvt_w_kernel(
    const float* __restrict__ Wx, const float* __restrict__ Wy, const float* __restrict__ Wo,
    u16* __restrict__ WxT, u16* __restrict__ WyT, u16* __restrict__ WoT)
{
    const int bid = blockIdx.x, t = threadIdx.x;
#pragma unroll
    for (int kk = 0; kk < 2; ++kk) {
        const int k = t + kk * 256;
        if (bid < 256)      WxT[(size_t)bid * NC + k] = f16b(Wx[(size_t)k * NCI + bid]);
        else if (bid < 512) WyT[(size_t)(bid - 256) * NC + k] = f16b(Wy[(size_t)k * NCI + (bid - 256)]);
        else                WoT[(size_t)(bid - 512) * NC + k] = f16b(Wo[(size_t)k * NC + (bid - 512)]);
    }
}

// ---- projections: grid (128, 8); cb 0-1 xp, 2-3 yp, 4-7 op (transposed) ----
// A staged from X fp32 via reg convert (cvt_x fused away).
__global__ __launch_bounds__(256) void proj_kernel(
    const float* __restrict__ X,
    const u16* __restrict__ WxT, const u16* __restrict__ WyT, const u16* __restrict__ WoT,
    const float* __restrict__ bx, const float* __restrict__ by, const float* __restrict__ bo,
    u16* __restrict__ xp, u16* __restrict__ yp, u16* __restrict__ opT)
{
    __shared__ __align__(16) u16 SM[17408];   // As 8192 + Bs 8192; Ts reuse 128x136
    u16* As = SM;
    u16* Bs = SM + 8192;

    const int tid = threadIdx.x;
    const int w = tid >> 6, lane = tid & 63;
    const int row0 = blockIdx.x * 128;
    const int cb = blockIdx.y;

    const u16* W; const float* bias; int n0, path;
    if (cb < 2)      { path = 0; n0 = cb * 128;       W = WxT; bias = bx; }
    else if (cb < 4) { path = 1; n0 = (cb - 2) * 128; W = WyT; bias = by; }
    else             { path = 2; n0 = (cb - 4) * 128; W = WoT; bias = bo; }

    f32x4 acc[4][4] = {};
    const int wm = (w & 1) * 64, wn = (w >> 1) * 64;
    const int fr = lane & 15, fq = lane >> 4;

    for (int k0 = 0; k0 < NC; k0 += 64) {
#pragma unroll
        for (int pass = 0; pass < 4; ++pass) {
            const int cbase = pass * 256 + w * 64;   // wave-uniform
            const int chunk = cbase + lane;
            const int r = chunk >> 3;
            const int kc = (chunk & 7) ^ (r & 7);    // XOR-swizzled k-chunk
            // A: reg-stage fp32 -> fp16 (cvt_x fused); same src<->slot mapping
            const float* xs = X + (size_t)(row0 + r) * NC + k0 + kc * 8;
            const float4 lo = *(const float4*)xs, hi = *(const float4*)(xs + 4);
            u16 o[8] = {f16b(lo.x), f16b(lo.y), f16b(lo.z), f16b(lo.w),
                        f16b(hi.x), f16b(hi.y), f16b(hi.z), f16b(hi.w)};
            *(uint4*)&As[chunk * 8] = *(const uint4*)o;
            gload16(W + (size_t)(n0 + r) * NC + k0 + kc * 8, (char*)Bs + cbase * 16);
        }
        __syncthreads();
        f16x8 a[4][2], b[4][2];
#pragma unroll
        for (int mi = 0; mi < 4; ++mi)
#pragma unroll
            for (int kt = 0; kt < 2; ++kt)
                a[mi][kt] = *(const f16x8*)&As[(wm + mi * 16 + fr) * 64 + ((kt * 4 + fq) ^ (fr & 7)) * 8];
#pragma unroll
        for (int ni = 0; ni < 4; ++ni)
#pragma unroll
            for (int kt = 0; kt < 2; ++kt)
                b[ni][kt] = *(const f16x8*)&Bs[(wn + ni * 16 + fr) * 64 + ((kt * 4 + fq) ^ (fr & 7)) * 8];
#pragma unroll
        for (int kt = 0; kt < 2; ++kt)
#pragma unroll
            for (int mi = 0; mi < 4; ++mi)
#pragma unroll
                for (int ni = 0; ni < 4; ++ni)
                    acc[mi][ni] = __builtin_amdgcn_mfma_f32_16x16x32_f16(a[mi][kt], b[ni][kt], acc[mi][ni], 0, 0, 0);
        __syncthreads();
    }

    if (path != 2) {
        u16* O = (path == 0) ? xp : yp;
#pragma unroll
        for (int mi = 0; mi < 4; ++mi) {
            const int grow = row0 + wm + mi * 16 + fq * 4;
#pragma unroll
            for (int ni = 0; ni < 4; ++ni) {
                const int gcol = n0 + wn + ni * 16 + fr;
                const float bv = bias[gcol];
#pragma unroll
                for (int r = 0; r < 4; ++r)
                    O[(size_t)(grow + r) * NCI + gcol] = f16b(acc[mi][ni][r] + bv);
            }
        }
    } else {
        u16* Ts = SM;   // 128 x 136 fp16 transpose staging
#pragma unroll
        for (int mi = 0; mi < 4; ++mi) {
            const int mb = wm + mi * 16 + fq * 4;
#pragma unroll
            for (int ni = 0; ni < 4; ++ni) {
                const int nl_ = wn + ni * 16 + fr;
                const float bv = bias[n0 + nl_];
#pragma unroll
                for (int r = 0; r < 4; ++r)
                    Ts[nl_ * 136 + mb + r] = f16b(acc[mi][ni][r] + bv);
            }
        }
        __syncthreads();
        const int b = row0 >> 11, m0 = row0 & 2047;
        u16* dst = opT + (size_t)b * NC * NL + (size_t)n0 * NL + m0;
        for (int i = tid; i < 128 * 16; i += 256) {
            const int c = i >> 4, ch = i & 15;
            uint4 v = *(const uint4*)&Ts[c * 136 + ch * 8];
            *(uint4*)&dst[(size_t)c * NL + ch * 8] = v;
        }
    }
}

// ---- FUSED score+softmax --------------------------------------------------
// r15 structure + r17 XCD patch swizzle. Epilogue: regs -> softmax ->
// per-batch planes (pitch 72, 16B-aligned) -> vectorized uint4 ATT stores.
__global__ __launch_bounds__(512, 4) void score_softmax_kernel(
    const u16* __restrict__ xp, const u16* __restrict__ yp, u16* __restrict__ ATT)
{
    // staging [0,32768) | exchange [(r*65+c)*8+b, max 33272) | planes 8x4608
    __shared__ __align__(16) u16 SM[36864];   // 72 KB, 2 blocks/CU
    const int tid = threadIdx.x;
    const int w = tid >> 6, lane = tid & 63;

    // XCD patch remap (bijective: 8 patches x 128 slots = 1024 blocks)
    const int L = blockIdx.x + 32 * blockIdx.y;
    const int xcd = L & 7, slot = L >> 3;
    const int bx = (xcd >> 1) * 8 + (slot & 7);    // row-tile 0..31
    const int by = (xcd & 1) * 16 + (slot >> 3);   // col-tile 0..31
    const int row0 = bx * 64, col0 = by * 64;

    const int bb = w & 3, nh = w >> 2;
    const int fr = lane & 15, fq = lane >> 4;

    const int rs = (tid >> 3) & 63;          // staging row 0..63
    const int jj = (tid & 7) ^ (rs & 7);     // XOR-swizzled k-chunk

    unsigned sv[2][16];   // [g][mi*4+ni*2+rp] packed fp16 pairs

#pragma unroll
    for (int g = 0; g < 2; ++g) {
        f32x4 acc[4][2] = {};
#pragma unroll
        for (int s = 0; s < 4; ++s) {
            const int k0 = s * 64;
            // stage 4 batches' A+B 64x64 k-chunk tiles (4096 chunks, 8 passes)
#pragma unroll
            for (int pass = 0; pass < 8; ++pass) {
                const int ab = pass >> 2, b2 = pass & 3;   // wave-uniform
                const u16* src = (ab ? yp : xp)
                    + (size_t)(g * 4 + b2) * NL * NCI
                    + (size_t)((ab ? col0 : row0) + rs) * NCI + k0 + jj * 8;
                gload16(src, (char*)SM + pass * 8192 + tid * 16);
            }
            __syncthreads();
#pragma unroll
            for (int kt = 0; kt < 2; ++kt) {
                const int coff = ((kt * 4 + fq) ^ (fr & 7)) * 8;
                f16x8 af[4], bf[2];
#pragma unroll
                for (int mi = 0; mi < 4; ++mi)
                    af[mi] = *(const f16x8*)&SM[bb * 4096 + (mi * 16 + fr) * 64 + coff];
#pragma unroll
                for (int ni = 0; ni < 2; ++ni)
                    bf[ni] = *(const f16x8*)&SM[16384 + bb * 4096 + (nh * 32 + ni * 16 + fr) * 64 + coff];
#pragma unroll
                for (int mi = 0; mi < 4; ++mi)
#pragma unroll
                    for (int ni = 0; ni < 2; ++ni)
                        acc[mi][ni] = __builtin_amdgcn_mfma_f32_16x16x32_f16(af[mi], bf[ni], acc[mi][ni], 0, 0, 0);
            }
            __syncthreads();
        }
#pragma unroll
        for (int mi = 0; mi < 4; ++mi)
#pragma unroll
            for (int ni = 0; ni < 2; ++ni) {
                sv[g][mi * 4 + ni * 2 + 0] = (unsigned)f16b(acc[mi][ni][0]) | ((unsigned)f16b(acc[mi][ni][1]) << 16);
                sv[g][mi * 4 + ni * 2 + 1] = (unsigned)f16b(acc[mi][ni][2]) | ((unsigned)f16b(acc[mi][ni][3]) << 16);
            }
    }

    // phase 1: exchange raw scores -> SM[(row*65+col)*8 + b]
#pragma unroll
    for (int g = 0; g < 2; ++g)
#pragma unroll
        for (int mi = 0; mi < 4; ++mi)
#pragma unroll
            for (int ni = 0; ni < 2; ++ni)
#pragma unroll
                for (int rp = 0; rp < 2; ++rp) {
                    const unsigned u = sv[g][mi * 4 + ni * 2 + rp];
                    const int r_ = mi * 16 + fq * 4 + rp * 2;
                    const int c_ = nh * 32 + ni * 16 + fr;
                    SM[(r_ * 65 + c_) * 8 + g * 4 + bb]         = (u16)(u & 0xFFFF);
                    SM[((r_ + 1) * 65 + c_) * 8 + g * 4 + bb]   = (u16)(u >> 16);
                }
    __syncthreads();

    // phase 2: read all 8 slots (all 8 b each) into regs
    uint4 v8[8];
#pragma unroll
    for (int j = 0; j < 8; ++j) {
        const int row = j * 8 + w;
        v8[j] = *(const uint4*)&SM[(row * 65 + lane) * 8];
    }
    __syncthreads();   // all exchange reads done; SM reusable

    // phase 3: softmax per slot, write normalized to planes [b][row 72][col]
#pragma unroll
    for (int j = 0; j < 8; ++j) {
        const int row = j * 8 + w;
        const uint4 v = v8[j];
        float f[NB];
        f[0] = f16tof((u16)(v.x & 0xFFFF)); f[1] = f16tof((u16)(v.x >> 16));
        f[2] = f16tof((u16)(v.y & 0xFFFF)); f[3] = f16tof((u16)(v.y >> 16));
        f[4] = f16tof((u16)(v.z & 0xFFFF)); f[5] = f16tof((u16)(v.z >> 16));
        f[6] = f16tof((u16)(v.w & 0xFFFF)); f[7] = f16tof((u16)(v.w >> 16));
        float m = f[0];
#pragma unroll
        for (int b = 1; b < NB; ++b) m = fmaxf(m, f[b]);
        float ssum = 0.f;
#pragma unroll
        for (int b = 0; b < NB; ++b) { f[b] = __expf(f[b] - m); ssum += f[b]; }
        const float inv = 1.f / ssum;
#pragma unroll
        for (int b = 0; b < NB; ++b)
            SM[b * 4608 + row * 72 + lane] = f16b(f[b] * inv);   // 2B/lane: free
    }
    __syncthreads();

    // phase 4: vectorized ATT write (uint4, 8 per thread; 16B-aligned: 72%8==0)
#pragma unroll
    for (int i = 0; i < 8; ++i) {
        const int q = i * 512 + tid;
        const int b = q >> 9, rem = q & 511;
        const int row = rem >> 3, cg = rem & 7;
        const uint4 val = *(const uint4*)&SM[b * 4608 + row * 72 + cg * 8];
        *(uint4*)&ATT[(size_t)b * NL * NL + (size_t)(row0 + row) * NL + col0 + cg * 8] = val;
    }
}

// ---- out: out[b] = X[b] + attn[b] @ op[b], 512 thr ------------------------
// r16 serial BK=128 stacked-64-half staging; r13 bijective XCD chunk swizzle.
__global__ __launch_bounds__(512) void out_kernel(
    const u16* __restrict__ ATT, const u16* __restrict__ opT,
    const float* __restrict__ X, float* __restrict__ Out)
{
    __shared__ __align__(16) u16 As[16384], Bs[16384];   // 2x(128x64) u16 each
    const int tid = threadIdx.x;
    const int w = tid >> 6, lane = tid & 63;

    // linear dispatch id (x-fastest) -> XCD-chunked remap (bijective: 512%8==0)
    const int id  = blockIdx.x + 16 * (blockIdx.y + 4 * blockIdx.z);
    const int nid = (id & 7) * 64 + (id >> 3);   // chunk = 512/8 = 64
    const int bx  = nid & 15;                    // row tile 0..15
    const int by  = (nid >> 4) & 3;              // col tile 0..3
    const int b   = nid >> 6;                    // batch 0..7

    const int row0 = bx * 128, col0 = by * 128;
    const u16* Aatt = ATT + (size_t)b * NL * NL;
    const u16* Bsrc = opT + (size_t)b * NC * NL;

    f32x4 acc[4][2] = {};
    const int wm = (w & 1) * 64, wn = (w >> 1) * 32;
    const int fr = lane & 15, fq = lane >> 4;

    for (int it = 0; it < NL / 128; ++it) {
        const int k0 = it * 128;
        // stage A,B 128x128 as stacked 64-k halves (2048 chunks, 4 passes)
#pragma unroll
        for (int pass = 0; pass < 4; ++pass) {
            const int c = pass * 512 + tid;
            const int kh = c >> 10;              // 0..1 (1024 chunks per half)
            const int r = (c >> 3) & 127;        // row 0..127
            const int jj = (c & 7) ^ (r & 7);    // XOR-swizzled k-chunk
            const int srck = k0 + kh * 64 + jj * 8;
            gload16(Aatt + (size_t)(row0 + r) * NL + srck, (char*)As + c * 16);
            gload16(Bsrc + (size_t)(col0 + r) * NL + srck, (char*)Bs + c * 16);
        }
        __syncthreads();
#pragma unroll
        for (int kh = 0; kh < 2; ++kh)
#pragma unroll
            for (int kt = 0; kt < 2; ++kt) {
                const int hb = kh * 8192;
                const int coff = ((kt * 4 + fq) ^ (fr & 7)) * 8;
                f16x8 af[4], bf[2];
#pragma unroll
                for (int mi = 0; mi < 4; ++mi)
                    af[mi] = *(const f16x8*)&As[hb + (wm + mi * 16 + fr) * 64 + coff];
#pragma unroll
                for (int ni = 0; ni < 2; ++ni)
                    bf[ni] = *(const f16x8*)&Bs[hb + (wn + ni * 16 + fr) * 64 + coff];
#pragma unroll
                for (int mi = 0; mi < 4; ++mi)
#pragma unroll
                    for (int ni = 0; ni < 2; ++ni)
                        acc[mi][ni] = __builtin_amdgcn_mfma_f32_16x16x32_f16(af[mi], bf[ni], acc[mi][ni], 0, 0, 0);
            }
        __syncthreads();
    }
    const size_t ob = (size_t)b * NL * NC;
#pragma unroll
    for (int mi = 0; mi < 4; ++mi) {
        const int gr = row0 + wm + mi * 16 + fq * 4;
#pragma unroll
        for (int ni = 0; ni < 2; ++ni) {
            const int gc = col0 + wn + ni * 16 + fr;
#pragma unroll
            for (int r = 0; r < 4; ++r) {
                const size_t o = ob + (size_t)(gr + r) * NC + gc;
                Out[o] = X[o] + acc[mi][ni][r];
            }
        }
    }
}

extern "C" void kernel_launch(void* const* d_in, const int* in_sizes, int n_in,
                              void* d_out, int out_size, void* d_ws, size_t ws_size,
                              hipStream_t stream)
{
    const float* X  = (const float*)d_in[0];
    const float* Wx = (const float*)d_in[1];
    const float* bx = (const float*)d_in[2];
    const float* Wy = (const float*)d_in[3];
    const float* by = (const float*)d_in[4];
    const float* Wo = (const float*)d_in[5];
    const float* bo = (const float*)d_in[6];
    float* out = (float*)d_out;

    // Workspace (~97 MB): ATT fp16 [0,64MB).
    char* ws = (char*)d_ws;
    u16* ATT = (u16*)ws;
    char* p = ws + 67108864;
    u16* xp  = (u16*)p; p += 8388608;
    u16* yp  = (u16*)p; p += 8388608;
    u16* opT = (u16*)p; p += 16777216;
    u16* WxT = (u16*)p; p += 262144;
    u16* WyT = (u16*)p; p += 262144;
    u16* WoT = (u16*)p; p += 524288;

    cvt_w_kernel<<<1024, 256, 0, stream>>>(Wx, Wy, Wo, WxT, WyT, WoT);
    proj_kernel<<<dim3(128, 8), 256, 0, stream>>>(X, WxT, WyT, WoT, bx, by, bo, xp, yp, opT);
    score_softmax_kernel<<<dim3(32, 32), 512, 0, stream>>>(xp, yp, ATT);
    out_kernel<<<dim3(16, 4, NB), 512, 0, stream>>>(ATT, opT, X, out);
}

// Round 14
// 204.252 us; speedup vs baseline: 1.0170x; 1.0170x over previous
//
#include <hip/hip_runtime.h>

// NonLocalBlock B=8, L=2048, C=512, CI=256 (fp32 in/out).
// Round 20 (recomposition of benched-best pieces):
//   - cvt_x RESTORED; proj back to r17 gload16 async A-staging. r19's fused
//     reg-staged convert cost proj +11us (> cvt_x's 9us): blocking loads +
//     2x fp32 bytes + 196K ds_write conflicts (m151: reg-staging loses to
//     global_load_lds where linear LDS works). Net revert.
//   - score_softmax: KEEP r19 epilogue (score left the top-5: regs ->
//     softmax -> per-batch planes pitch 72 (16B-aligned) -> uint4 stores)
//     + r15 batch-parallel GEMM + r17 XCD patch swizzle.
//   - out_kernel: r16 serial BK=128 + r13 XCD chunk swizzle unchanged.
//   All-fp16, XOR k-chunk swizzle.

#define NB 8
#define NL 2048
#define NC 512
#define NCI 256

using f16x8 = __attribute__((ext_vector_type(8))) _Float16;
using f32x4 = __attribute__((ext_vector_type(4))) float;
typedef unsigned short u16;

__device__ __forceinline__ u16 f16b(float x) {
    _Float16 h = (_Float16)x;
    return __builtin_bit_cast(u16, h);
}
__device__ __forceinline__ float f16tof(u16 u) {
    return (float)__builtin_bit_cast(_Float16, u);
}
__device__ __forceinline__ void gload16(const void* g, void* l) {
    __builtin_amdgcn_global_load_lds((__attribute__((address_space(1))) void*)g,
                                     (__attribute__((address_space(3))) void*)l,
                                     16, 0, 0);
}

// ---- cvt: X fp32 -> fp16 --------------------------------------------------
__global__ __launch_bounds__(256) void cvt_x_kernel(const float* __restrict__ X,
                                                    u16* __restrict__ Xf)
{
    size_t i = (size_t)blockIdx.x * 256 + threadIdx.x;   // per 8 elements
    const float4* X4 = (const float4*)X;
    float4 a = X4[2 * i], b = X4[2 * i + 1];
    u16 o[8] = {f16b(a.x), f16b(a.y), f16b(a.z), f16b(a.w),
                f16b(b.x), f16b(b.y), f16b(b.z), f16b(b.w)};
    ((uint4*)Xf)[i] = *(const uint4*)o;
}

// ---- cvt: transpose weights to [n][k] fp16 --------------------------------
__global__ __launch_bounds__(256) void cvt_w_kernel(
    const float* __restrict__ Wx, const float* __restrict__ Wy, const float* __restrict__ Wo,
    u16* __restrict__ WxT, u16* __restrict__ WyT, u16* __restrict__ WoT)
{
    const int bid = blockIdx.x, t = threadIdx.x;
#pragma unroll
    for (int kk = 0; kk < 2; ++kk) {
        const int k = t + kk * 256;
        if (bid < 256)      WxT[(size_t)bid * NC + k] = f16b(Wx[(size_t)k * NCI + bid]);
        else if (bid < 512) WyT[(size_t)(bid - 256) * NC + k] = f16b(Wy[(size_t)k * NCI + (bid - 256)]);
        else                WoT[(size_t)(bid - 512) * NC + k] = f16b(Wo[(size_t)k * NC + (bid - 512)]);
    }
}

// ---- projections: grid (128, 8); cb 0-1 xp, 2-3 yp, 4-7 op (transposed) ----
__global__ __launch_bounds__(256) void proj_kernel(
    const u16* __restrict__ Xf,
    const u16* __restrict__ WxT, const u16* __restrict__ WyT, const u16* __restrict__ WoT,
    const float* __restrict__ bx, const float* __restrict__ by, const float* __restrict__ bo,
    u16* __restrict__ xp, u16* __restrict__ yp, u16* __restrict__ opT)
{
    __shared__ __align__(16) u16 SM[17408];   // As 8192 + Bs 8192; Ts reuse 128x136
    u16* As = SM;
    u16* Bs = SM + 8192;

    const int tid = threadIdx.x;
    const int w = tid >> 6, lane = tid & 63;
    const int row0 = blockIdx.x * 128;
    const int cb = blockIdx.y;

    const u16* W; const float* bias; int n0, path;
    if (cb < 2)      { path = 0; n0 = cb * 128;       W = WxT; bias = bx; }
    else if (cb < 4) { path = 1; n0 = (cb - 2) * 128; W = WyT; bias = by; }
    else             { path = 2; n0 = (cb - 4) * 128; W = WoT; bias = bo; }

    f32x4 acc[4][4] = {};
    const int wm = (w & 1) * 64, wn = (w >> 1) * 64;
    const int fr = lane & 15, fq = lane >> 4;

    for (int k0 = 0; k0 < NC; k0 += 64) {
#pragma unroll
        for (int pass = 0; pass < 4; ++pass) {
            const int cbase = pass * 256 + w * 64;   // wave-uniform
            const int chunk = cbase + lane;
            const int r = chunk >> 3;
            const int kc = (chunk & 7) ^ (r & 7);    // XOR-swizzled k-chunk
            gload16(Xf + (size_t)(row0 + r) * NC + k0 + kc * 8, (char*)As + cbase * 16);
            gload16(W  + (size_t)(n0  + r) * NC + k0 + kc * 8, (char*)Bs + cbase * 16);
        }
        __syncthreads();
        f16x8 a[4][2], b[4][2];
#pragma unroll
        for (int mi = 0; mi < 4; ++mi)
#pragma unroll
            for (int kt = 0; kt < 2; ++kt)
                a[mi][kt] = *(const f16x8*)&As[(wm + mi * 16 + fr) * 64 + ((kt * 4 + fq) ^ (fr & 7)) * 8];
#pragma unroll
        for (int ni = 0; ni < 4; ++ni)
#pragma unroll
            for (int kt = 0; kt < 2; ++kt)
                b[ni][kt] = *(const f16x8*)&Bs[(wn + ni * 16 + fr) * 64 + ((kt * 4 + fq) ^ (fr & 7)) * 8];
#pragma unroll
        for (int kt = 0; kt < 2; ++kt)
#pragma unroll
            for (int mi = 0; mi < 4; ++mi)
#pragma unroll
                for (int ni = 0; ni < 4; ++ni)
                    acc[mi][ni] = __builtin_amdgcn_mfma_f32_16x16x32_f16(a[mi][kt], b[ni][kt], acc[mi][ni], 0, 0, 0);
        __syncthreads();
    }

    if (path != 2) {
        u16* O = (path == 0) ? xp : yp;
#pragma unroll
        for (int mi = 0; mi < 4; ++mi) {
            const int grow = row0 + wm + mi * 16 + fq * 4;
#pragma unroll
            for (int ni = 0; ni < 4; ++ni) {
                const int gcol = n0 + wn + ni * 16 + fr;
                const float bv = bias[gcol];
#pragma unroll
                for (int r = 0; r < 4; ++r)
                    O[(size_t)(grow + r) * NCI + gcol] = f16b(acc[mi][ni][r] + bv);
            }
        }
    } else {
        u16* Ts = SM;   // 128 x 136 fp16 transpose staging
#pragma unroll
        for (int mi = 0; mi < 4; ++mi) {
            const int mb = wm + mi * 16 + fq * 4;
#pragma unroll
            for (int ni = 0; ni < 4; ++ni) {
                const int nl_ = wn + ni * 16 + fr;
                const float bv = bias[n0 + nl_];
#pragma unroll
                for (int r = 0; r < 4; ++r)
                    Ts[nl_ * 136 + mb + r] = f16b(acc[mi][ni][r] + bv);
            }
        }
        __syncthreads();
        const int b = row0 >> 11, m0 = row0 & 2047;
        u16* dst = opT + (size_t)b * NC * NL + (size_t)n0 * NL + m0;
        for (int i = tid; i < 128 * 16; i += 256) {
            const int c = i >> 4, ch = i & 15;
            uint4 v = *(const uint4*)&Ts[c * 136 + ch * 8];
            *(uint4*)&dst[(size_t)c * NL + ch * 8] = v;
        }
    }
}

// ---- FUSED score+softmax --------------------------------------------------
// r15 structure + r17 XCD patch swizzle + r19 plane epilogue (pitch 72).
__global__ __launch_bounds__(512, 4) void score_softmax_kernel(
    const u16* __restrict__ xp, const u16* __restrict__ yp, u16* __restrict__ ATT)
{
    // staging [0,32768) | exchange [(r*65+c)*8+b, max 33272) | planes 8x4608
    __shared__ __align__(16) u16 SM[36864];   // 72 KB, 2 blocks/CU
    const int tid = threadIdx.x;
    const int w = tid >> 6, lane = tid & 63;

    // XCD patch remap (bijective: 8 patches x 128 slots = 1024 blocks)
    const int L = blockIdx.x + 32 * blockIdx.y;
    const int xcd = L & 7, slot = L >> 3;
    const int bx = (xcd >> 1) * 8 + (slot & 7);    // row-tile 0..31
    const int by = (xcd & 1) * 16 + (slot >> 3);   // col-tile 0..31
    const int row0 = bx * 64, col0 = by * 64;

    const int bb = w & 3, nh = w >> 2;
    const int fr = lane & 15, fq = lane >> 4;

    const int rs = (tid >> 3) & 63;          // staging row 0..63
    const int jj = (tid & 7) ^ (rs & 7);     // XOR-swizzled k-chunk

    unsigned sv[2][16];   // [g][mi*4+ni*2+rp] packed fp16 pairs

#pragma unroll
    for (int g = 0; g < 2; ++g) {
        f32x4 acc[4][2] = {};
#pragma unroll
        for (int s = 0; s < 4; ++s) {
            const int k0 = s * 64;
            // stage 4 batches' A+B 64x64 k-chunk tiles (4096 chunks, 8 passes)
#pragma unroll
            for (int pass = 0; pass < 8; ++pass) {
                const int ab = pass >> 2, b2 = pass & 3;   // wave-uniform
                const u16* src = (ab ? yp : xp)
                    + (size_t)(g * 4 + b2) * NL * NCI
                    + (size_t)((ab ? col0 : row0) + rs) * NCI + k0 + jj * 8;
                gload16(src, (char*)SM + pass * 8192 + tid * 16);
            }
            __syncthreads();
#pragma unroll
            for (int kt = 0; kt < 2; ++kt) {
                const int coff = ((kt * 4 + fq) ^ (fr & 7)) * 8;
                f16x8 af[4], bf[2];
#pragma unroll
                for (int mi = 0; mi < 4; ++mi)
                    af[mi] = *(const f16x8*)&SM[bb * 4096 + (mi * 16 + fr) * 64 + coff];
#pragma unroll
                for (int ni = 0; ni < 2; ++ni)
                    bf[ni] = *(const f16x8*)&SM[16384 + bb * 4096 + (nh * 32 + ni * 16 + fr) * 64 + coff];
#pragma unroll
                for (int mi = 0; mi < 4; ++mi)
#pragma unroll
                    for (int ni = 0; ni < 2; ++ni)
                        acc[mi][ni] = __builtin_amdgcn_mfma_f32_16x16x32_f16(af[mi], bf[ni], acc[mi][ni], 0, 0, 0);
            }
            __syncthreads();
        }
#pragma unroll
        for (int mi = 0; mi < 4; ++mi)
#pragma unroll
            for (int ni = 0; ni < 2; ++ni) {
                sv[g][mi * 4 + ni * 2 + 0] = (unsigned)f16b(acc[mi][ni][0]) | ((unsigned)f16b(acc[mi][ni][1]) << 16);
                sv[g][mi * 4 + ni * 2 + 1] = (unsigned)f16b(acc[mi][ni][2]) | ((unsigned)f16b(acc[mi][ni][3]) << 16);
            }
    }

    // phase 1: exchange raw scores -> SM[(row*65+col)*8 + b]
#pragma unroll
    for (int g = 0; g < 2; ++g)
#pragma unroll
        for (int mi = 0; mi < 4; ++mi)
#pragma unroll
            for (int ni = 0; ni < 2; ++ni)
#pragma unroll
                for (int rp = 0; rp < 2; ++rp) {
                    const unsigned u = sv[g][mi * 4 + ni * 2 + rp];
                    const int r_ = mi * 16 + fq * 4 + rp * 2;
                    const int c_ = nh * 32 + ni * 16 + fr;
                    SM[(r_ * 65 + c_) * 8 + g * 4 + bb]         = (u16)(u & 0xFFFF);
                    SM[((r_ + 1) * 65 + c_) * 8 + g * 4 + bb]   = (u16)(u >> 16);
                }
    __syncthreads();

    // phase 2: read all 8 slots (all 8 b each) into regs
    uint4 v8[8];
#pragma unroll
    for (int j = 0; j < 8; ++j) {
        const int row = j * 8 + w;
        v8[j] = *(const uint4*)&SM[(row * 65 + lane) * 8];
    }
    __syncthreads();   // all exchange reads done; SM reusable

    // phase 3: softmax per slot, write normalized to planes [b][row 72][col]
#pragma unroll
    for (int j = 0; j < 8; ++j) {
        const int row = j * 8 + w;
        const uint4 v = v8[j];
        float f[NB];
        f[0] = f16tof((u16)(v.x & 0xFFFF)); f[1] = f16tof((u16)(v.x >> 16));
        f[2] = f16tof((u16)(v.y & 0xFFFF)); f[3] = f16tof((u16)(v.y >> 16));
        f[4] = f16tof((u16)(v.z & 0xFFFF)); f[5] = f16tof((u16)(v.z >> 16));
        f[6] = f16tof((u16)(v.w & 0xFFFF)); f[7] = f16tof((u16)(v.w >> 16));
        float m = f[0];
#pragma unroll
        for (int b = 1; b < NB; ++b) m = fmaxf(m, f[b]);
        float ssum = 0.f;
#pragma unroll
        for (int b = 0; b < NB; ++b) { f[b] = __expf(f[b] - m); ssum += f[b]; }
        const float inv = 1.f / ssum;
#pragma unroll
        for (int b = 0; b < NB; ++b)
            SM[b * 4608 + row * 72 + lane] = f16b(f[b] * inv);   // 2B/lane: free
    }
    __syncthreads();

    // phase 4: vectorized ATT write (uint4, 8 per thread; 16B-aligned: 72%8==0)
#pragma unroll
    for (int i = 0; i < 8; ++i) {
        const int q = i * 512 + tid;
        const int b = q >> 9, rem = q & 511;
        const int row = rem >> 3, cg = rem & 7;
        const uint4 val = *(const uint4*)&SM[b * 4608 + row * 72 + cg * 8];
        *(uint4*)&ATT[(size_t)b * NL * NL + (size_t)(row0 + row) * NL + col0 + cg * 8] = val;
    }
}

// ---- out: out[b] = X[b] + attn[b] @ op[b], 512 thr ------------------------
// r16 serial BK=128 stacked-64-half staging; r13 bijective XCD chunk swizzle.
__global__ __launch_bounds__(512) void out_kernel(
    const u16* __restrict__ ATT, const u16* __restrict__ opT,
    const float* __restrict__ X, float* __restrict__ Out)
{
    __shared__ __align__(16) u16 As[16384], Bs[16384];   // 2x(128x64) u16 each
    const int tid = threadIdx.x;
    const int w = tid >> 6, lane = tid & 63;

    // linear dispatch id (x-fastest) -> XCD-chunked remap (bijective: 512%8==0)
    const int id  = blockIdx.x + 16 * (blockIdx.y + 4 * blockIdx.z);
    const int nid = (id & 7) * 64 + (id >> 3);   // chunk = 512/8 = 64
    const int bx  = nid & 15;                    // row tile 0..15
    const int by  = (nid >> 4) & 3;              // col tile 0..3
    const int b   = nid >> 6;                    // batch 0..7

    const int row0 = bx * 128, col0 = by * 128;
    const u16* Aatt = ATT + (size_t)b * NL * NL;
    const u16* Bsrc = opT + (size_t)b * NC * NL;

    f32x4 acc[4][2] = {};
    const int wm = (w & 1) * 64, wn = (w >> 1) * 32;
    const int fr = lane & 15, fq = lane >> 4;

    for (int it = 0; it < NL / 128; ++it) {
        const int k0 = it * 128;
        // stage A,B 128x128 as stacked 64-k halves (2048 chunks, 4 passes)
#pragma unroll
        for (int pass = 0; pass < 4; ++pass) {
            const int c = pass * 512 + tid;
            const int kh = c >> 10;              // 0..1 (1024 chunks per half)
            const int r = (c >> 3) & 127;        // row 0..127
            const int jj = (c & 7) ^ (r & 7);    // XOR-swizzled k-chunk
            const int srck = k0 + kh * 64 + jj * 8;
            gload16(Aatt + (size_t)(row0 + r) * NL + srck, (char*)As + c * 16);
            gload16(Bsrc + (size_t)(col0 + r) * NL + srck, (char*)Bs + c * 16);
        }
        __syncthreads();
#pragma unroll
        for (int kh = 0; kh < 2; ++kh)
#pragma unroll
            for (int kt = 0; kt < 2; ++kt) {
                const int hb = kh * 8192;
                const int coff = ((kt * 4 + fq) ^ (fr & 7)) * 8;
                f16x8 af[4], bf[2];
#pragma unroll
                for (int mi = 0; mi < 4; ++mi)
                    af[mi] = *(const f16x8*)&As[hb + (wm + mi * 16 + fr) * 64 + coff];
#pragma unroll
                for (int ni = 0; ni < 2; ++ni)
                    bf[ni] = *(const f16x8*)&Bs[hb + (wn + ni * 16 + fr) * 64 + coff];
#pragma unroll
                for (int mi = 0; mi < 4; ++mi)
#pragma unroll
                    for (int ni = 0; ni < 2; ++ni)
                        acc[mi][ni] = __builtin_amdgcn_mfma_f32_16x16x32_f16(af[mi], bf[ni], acc[mi][ni], 0, 0, 0);
            }
        __syncthreads();
    }
    const size_t ob = (size_t)b * NL * NC;
#pragma unroll
    for (int mi = 0; mi < 4; ++mi) {
        const int gr = row0 + wm + mi * 16 + fq * 4;
#pragma unroll
        for (int ni = 0; ni < 2; ++ni) {
            const int gc = col0 + wn + ni * 16 + fr;
#pragma unroll
            for (int r = 0; r < 4; ++r) {
                const size_t o = ob + (size_t)(gr + r) * NC + gc;
                Out[o] = X[o] + acc[mi][ni][r];
            }
        }
    }
}

extern "C" void kernel_launch(void* const* d_in, const int* in_sizes, int n_in,
                              void* d_out, int out_size, void* d_ws, size_t ws_size,
                              hipStream_t stream)
{
    const float* X  = (const float*)d_in[0];
    const float* Wx = (const float*)d_in[1];
    const float* bx = (const float*)d_in[2];
    const float* Wy = (const float*)d_in[3];
    const float* by = (const float*)d_in[4];
    const float* Wo = (const float*)d_in[5];
    const float* bo = (const float*)d_in[6];
    float* out = (float*)d_out;

    // Workspace (~97 MB): ATT fp16 [0,64MB); Xf16 (16MB) overlaps ATT[0:16MB) —
    // dead (proj done) before score_softmax writes ATT (stream-ordered).
    char* ws = (char*)d_ws;
    u16* ATT = (u16*)ws;
    u16* Xf  = (u16*)ws;
    char* p = ws + 67108864;
    u16* xp  = (u16*)p; p += 8388608;
    u16* yp  = (u16*)p; p += 8388608;
    u16* opT = (u16*)p; p += 16777216;
    u16* WxT = (u16*)p; p += 262144;
    u16* WyT = (u16*)p; p += 262144;
    u16* WoT = (u16*)p; p += 524288;

    cvt_x_kernel<<<4096, 256, 0, stream>>>(X, Xf);
    cvt_w_kernel<<<1024, 256, 0, stream>>>(Wx, Wy, Wo, WxT, WyT, WoT);
    proj_kernel<<<dim3(128, 8), 256, 0, stream>>>(Xf, WxT, WyT, WoT, bx, by, bo, xp, yp, opT);
    score_softmax_kernel<<<dim3(32, 32), 512, 0, stream>>>(xp, yp, ATT);
    out_kernel<<<dim3(16, 4, NB), 512, 0, stream>>>(ATT, opT, X, out);
}

// Round 15
// 199.452 us; speedup vs baseline: 1.0415x; 1.0241x over previous
//
#include <hip/hip_runtime.h>

// NonLocalBlock B=8, L=2048, C=512, CI=256 (fp32 in/out).
// Round 21 (best-benched recomposition):
//   - score_softmax: r15 batch-parallel GEMM + r17 XCD patch swizzle +
//     OLD simple epilogue (45.6us benched r16/r17; r19/r20 plane epilogue
//     was +2.3us and +0.3M conflicts -> reverted. "Left the top-5" in r19
//     was misattribution: proj had ballooned past it).
//   - proj: r17 gload16 async staging (r19 reg-staged fusion cost +11us).
//   - out: r16 serial BK=128 stacked halves + r13 bijective XCD swizzle.
//   - cvt_x + cvt_w MERGED into one dispatch (grid 5120, block branch):
//     saves one launch gap, zero risk.
//   All-fp16, XOR k-chunk swizzle.

#define NB 8
#define NL 2048
#define NC 512
#define NCI 256

using f16x8 = __attribute__((ext_vector_type(8))) _Float16;
using f32x4 = __attribute__((ext_vector_type(4))) float;
typedef unsigned short u16;

__device__ __forceinline__ u16 f16b(float x) {
    _Float16 h = (_Float16)x;
    return __builtin_bit_cast(u16, h);
}
__device__ __forceinline__ float f16tof(u16 u) {
    return (float)__builtin_bit_cast(_Float16, u);
}
__device__ __forceinline__ void gload16(const void* g, void* l) {
    __builtin_amdgcn_global_load_lds((__attribute__((address_space(1))) void*)g,
                                     (__attribute__((address_space(3))) void*)l,
                                     16, 0, 0);
}

// ---- cvt: X fp32->fp16 (blocks 0..4095) + W transpose (blocks 4096..5119) --
__global__ __launch_bounds__(256) void cvt_kernel(
    const float* __restrict__ X, u16* __restrict__ Xf,
    const float* __restrict__ Wx, const float* __restrict__ Wy, const float* __restrict__ Wo,
    u16* __restrict__ WxT, u16* __restrict__ WyT, u16* __restrict__ WoT)
{
    const int blk = blockIdx.x;
    if (blk < 4096) {
        size_t i = (size_t)blk * 256 + threadIdx.x;   // per 8 elements
        const float4* X4 = (const float4*)X;
        float4 a = X4[2 * i], b = X4[2 * i + 1];
        u16 o[8] = {f16b(a.x), f16b(a.y), f16b(a.z), f16b(a.w),
                    f16b(b.x), f16b(b.y), f16b(b.z), f16b(b.w)};
        ((uint4*)Xf)[i] = *(const uint4*)o;
    } else {
        const int bid = blk - 4096, t = threadIdx.x;
#pragma unroll
        for (int kk = 0; kk < 2; ++kk) {
            const int k = t + kk * 256;
            if (bid < 256)      WxT[(size_t)bid * NC + k] = f16b(Wx[(size_t)k * NCI + bid]);
            else if (bid < 512) WyT[(size_t)(bid - 256) * NC + k] = f16b(Wy[(size_t)k * NCI + (bid - 256)]);
            else                WoT[(size_t)(bid - 512) * NC + k] = f16b(Wo[(size_t)k * NC + (bid - 512)]);
        }
    }
}

// ---- projections: grid (128, 8); cb 0-1 xp, 2-3 yp, 4-7 op (transposed) ----
__global__ __launch_bounds__(256) void proj_kernel(
    const u16* __restrict__ Xf,
    const u16* __restrict__ WxT, const u16* __restrict__ WyT, const u16* __restrict__ WoT,
    const float* __restrict__ bx, const float* __restrict__ by, const float* __restrict__ bo,
    u16* __restrict__ xp, u16* __restrict__ yp, u16* __restrict__ opT)
{
    __shared__ __align__(16) u16 SM[17408];   // As 8192 + Bs 8192; Ts reuse 128x136
    u16* As = SM;
    u16* Bs = SM + 8192;

    const int tid = threadIdx.x;
    const int w = tid >> 6, lane = tid & 63;
    const int row0 = blockIdx.x * 128;
    const int cb = blockIdx.y;

    const u16* W; const float* bias; int n0, path;
    if (cb < 2)      { path = 0; n0 = cb * 128;       W = WxT; bias = bx; }
    else if (cb < 4) { path = 1; n0 = (cb - 2) * 128; W = WyT; bias = by; }
    else             { path = 2; n0 = (cb - 4) * 128; W = WoT; bias = bo; }

    f32x4 acc[4][4] = {};
    const int wm = (w & 1) * 64, wn = (w >> 1) * 64;
    const int fr = lane & 15, fq = lane >> 4;

    for (int k0 = 0; k0 < NC; k0 += 64) {
#pragma unroll
        for (int pass = 0; pass < 4; ++pass) {
            const int cbase = pass * 256 + w * 64;   // wave-uniform
            const int chunk = cbase + lane;
            const int r = chunk >> 3;
            const int kc = (chunk & 7) ^ (r & 7);    // XOR-swizzled k-chunk
            gload16(Xf + (size_t)(row0 + r) * NC + k0 + kc * 8, (char*)As + cbase * 16);
            gload16(W  + (size_t)(n0  + r) * NC + k0 + kc * 8, (char*)Bs + cbase * 16);
        }
        __syncthreads();
        f16x8 a[4][2], b[4][2];
#pragma unroll
        for (int mi = 0; mi < 4; ++mi)
#pragma unroll
            for (int kt = 0; kt < 2; ++kt)
                a[mi][kt] = *(const f16x8*)&As[(wm + mi * 16 + fr) * 64 + ((kt * 4 + fq) ^ (fr & 7)) * 8];
#pragma unroll
        for (int ni = 0; ni < 4; ++ni)
#pragma unroll
            for (int kt = 0; kt < 2; ++kt)
                b[ni][kt] = *(const f16x8*)&Bs[(wn + ni * 16 + fr) * 64 + ((kt * 4 + fq) ^ (fr & 7)) * 8];
#pragma unroll
        for (int kt = 0; kt < 2; ++kt)
#pragma unroll
            for (int mi = 0; mi < 4; ++mi)
#pragma unroll
                for (int ni = 0; ni < 4; ++ni)
                    acc[mi][ni] = __builtin_amdgcn_mfma_f32_16x16x32_f16(a[mi][kt], b[ni][kt], acc[mi][ni], 0, 0, 0);
        __syncthreads();
    }

    if (path != 2) {
        u16* O = (path == 0) ? xp : yp;
#pragma unroll
        for (int mi = 0; mi < 4; ++mi) {
            const int grow = row0 + wm + mi * 16 + fq * 4;
#pragma unroll
            for (int ni = 0; ni < 4; ++ni) {
                const int gcol = n0 + wn + ni * 16 + fr;
                const float bv = bias[gcol];
#pragma unroll
                for (int r = 0; r < 4; ++r)
                    O[(size_t)(grow + r) * NCI + gcol] = f16b(acc[mi][ni][r] + bv);
            }
        }
    } else {
        u16* Ts = SM;   // 128 x 136 fp16 transpose staging
#pragma unroll
        for (int mi = 0; mi < 4; ++mi) {
            const int mb = wm + mi * 16 + fq * 4;
#pragma unroll
            for (int ni = 0; ni < 4; ++ni) {
                const int nl_ = wn + ni * 16 + fr;
                const float bv = bias[n0 + nl_];
#pragma unroll
                for (int r = 0; r < 4; ++r)
                    Ts[nl_ * 136 + mb + r] = f16b(acc[mi][ni][r] + bv);
            }
        }
        __syncthreads();
        const int b = row0 >> 11, m0 = row0 & 2047;
        u16* dst = opT + (size_t)b * NC * NL + (size_t)n0 * NL + m0;
        for (int i = tid; i < 128 * 16; i += 256) {
            const int c = i >> 4, ch = i & 15;
            uint4 v = *(const uint4*)&Ts[c * 136 + ch * 8];
            *(uint4*)&dst[(size_t)c * NL + ch * 8] = v;
        }
    }
}

// ---- FUSED score+softmax --------------------------------------------------
// r15 structure: grid (32,32), 512 thr / 8 waves, 64x64 (l,m) tile, batches
// in 2 groups of 4; softmax via 65-padded LDS exchange (old epilogue).
// r17 XCD patch swizzle: XCD = linear_id & 7 owns an 8x16 tile patch.
__global__ __launch_bounds__(512, 4) void score_softmax_kernel(
    const u16* __restrict__ xp, const u16* __restrict__ yp, u16* __restrict__ ATT)
{
    // staging: A[bb] at bb*4096 (64x64 u16), B[bb] at 16384+bb*4096 (64 KB)
    // exchange: [row][col pad 65][b] u16 -> 33280 u16 = 66.5 KB total
    __shared__ __align__(16) u16 SM[33280];
    const int tid = threadIdx.x;
    const int w = tid >> 6, lane = tid & 63;

    // XCD patch remap (bijective: 8 patches x 128 slots = 1024 blocks)
    const int L = blockIdx.x + 32 * blockIdx.y;
    const int xcd = L & 7, slot = L >> 3;
    const int bx = (xcd >> 1) * 8 + (slot & 7);    // row-tile 0..31
    const int by = (xcd & 1) * 16 + (slot >> 3);   // col-tile 0..31
    const int row0 = bx * 64, col0 = by * 64;

    const int bb = w & 3, nh = w >> 2;
    const int fr = lane & 15, fq = lane >> 4;

    const int rs = (tid >> 3) & 63;          // staging row 0..63
    const int jj = (tid & 7) ^ (rs & 7);     // XOR-swizzled k-chunk

    unsigned sv[2][16];   // [g][mi*4+ni*2+rp] packed fp16 pairs

#pragma unroll
    for (int g = 0; g < 2; ++g) {
        f32x4 acc[4][2] = {};
#pragma unroll
        for (int s = 0; s < 4; ++s) {
            const int k0 = s * 64;
            // stage 4 batches' A+B 64x64 k-chunk tiles (4096 chunks, 8 passes)
#pragma unroll
            for (int pass = 0; pass < 8; ++pass) {
                const int ab = pass >> 2, b2 = pass & 3;   // wave-uniform
                const u16* src = (ab ? yp : xp)
                    + (size_t)(g * 4 + b2) * NL * NCI
                    + (size_t)((ab ? col0 : row0) + rs) * NCI + k0 + jj * 8;
                gload16(src, (char*)SM + pass * 8192 + tid * 16);
            }
            __syncthreads();
#pragma unroll
            for (int kt = 0; kt < 2; ++kt) {
                const int coff = ((kt * 4 + fq) ^ (fr & 7)) * 8;
                f16x8 af[4], bf[2];
#pragma unroll
                for (int mi = 0; mi < 4; ++mi)
                    af[mi] = *(const f16x8*)&SM[bb * 4096 + (mi * 16 + fr) * 64 + coff];
#pragma unroll
                for (int ni = 0; ni < 2; ++ni)
                    bf[ni] = *(const f16x8*)&SM[16384 + bb * 4096 + (nh * 32 + ni * 16 + fr) * 64 + coff];
#pragma unroll
                for (int mi = 0; mi < 4; ++mi)
#pragma unroll
                    for (int ni = 0; ni < 2; ++ni)
                        acc[mi][ni] = __builtin_amdgcn_mfma_f32_16x16x32_f16(af[mi], bf[ni], acc[mi][ni], 0, 0, 0);
            }
            __syncthreads();
        }
#pragma unroll
        for (int mi = 0; mi < 4; ++mi)
#pragma unroll
            for (int ni = 0; ni < 2; ++ni) {
                sv[g][mi * 4 + ni * 2 + 0] = (unsigned)f16b(acc[mi][ni][0]) | ((unsigned)f16b(acc[mi][ni][1]) << 16);
                sv[g][mi * 4 + ni * 2 + 1] = (unsigned)f16b(acc[mi][ni][2]) | ((unsigned)f16b(acc[mi][ni][3]) << 16);
            }
    }

    // exchange: scores -> SM[(row*65+col)*8 + b] (last stage barrier covers reads)
#pragma unroll
    for (int g = 0; g < 2; ++g)
#pragma unroll
        for (int mi = 0; mi < 4; ++mi)
#pragma unroll
            for (int ni = 0; ni < 2; ++ni)
#pragma unroll
                for (int rp = 0; rp < 2; ++rp) {
                    const unsigned u = sv[g][mi * 4 + ni * 2 + rp];
                    const int r_ = mi * 16 + fq * 4 + rp * 2;
                    const int c_ = nh * 32 + ni * 16 + fr;
                    SM[(r_ * 65 + c_) * 8 + g * 4 + bb]         = (u16)(u & 0xFFFF);
                    SM[((r_ + 1) * 65 + c_) * 8 + g * 4 + bb]   = (u16)(u >> 16);
                }
    __syncthreads();

    // softmax over b (8 contiguous u16 per slot = one b128 read), write ATT
#pragma unroll
    for (int j = 0; j < 8; ++j) {
        const int row = j * 8 + w;             // slot row 0..63
        const int col = lane;                  // slot col 0..63
        const uint4 v = *(const uint4*)&SM[(row * 65 + col) * 8];
        float f[NB];
        f[0] = f16tof((u16)(v.x & 0xFFFF)); f[1] = f16tof((u16)(v.x >> 16));
        f[2] = f16tof((u16)(v.y & 0xFFFF)); f[3] = f16tof((u16)(v.y >> 16));
        f[4] = f16tof((u16)(v.z & 0xFFFF)); f[5] = f16tof((u16)(v.z >> 16));
        f[6] = f16tof((u16)(v.w & 0xFFFF)); f[7] = f16tof((u16)(v.w >> 16));
        float m = f[0];
#pragma unroll
        for (int b = 1; b < NB; ++b) m = fmaxf(m, f[b]);
        float ssum = 0.f;
#pragma unroll
        for (int b = 0; b < NB; ++b) { f[b] = __expf(f[b] - m); ssum += f[b]; }
        const float inv = 1.f / ssum;
        const size_t go = (size_t)(row0 + row) * NL + col0 + col;
#pragma unroll
        for (int b = 0; b < NB; ++b)
            ATT[(size_t)b * NL * NL + go] = f16b(f[b] * inv);
    }
}

// ---- out: out[b] = X[b] + attn[b] @ op[b], 512 thr ------------------------
// r16 serial BK=128 stacked-64-half staging; r13 bijective XCD chunk swizzle.
__global__ __launch_bounds__(512) void out_kernel(
    const u16* __restrict__ ATT, const u16* __restrict__ opT,
    const float* __restrict__ X, float* __restrict__ Out)
{
    __shared__ __align__(16) u16 As[16384], Bs[16384];   // 2x(128x64) u16 each
    const int tid = threadIdx.x;
    const int w = tid >> 6, lane = tid & 63;

    // linear dispatch id (x-fastest) -> XCD-chunked remap (bijective: 512%8==0)
    const int id  = blockIdx.x + 16 * (blockIdx.y + 4 * blockIdx.z);
    const int nid = (id & 7) * 64 + (id >> 3);   // chunk = 512/8 = 64
    const int bx  = nid & 15;                    // row tile 0..15
    const int by  = (nid >> 4) & 3;              // col tile 0..3
    const int b   = nid >> 6;                    // batch 0..7

    const int row0 = bx * 128, col0 = by * 128;
    const u16* Aatt = ATT + (size_t)b * NL * NL;
    const u16* Bsrc = opT + (size_t)b * NC * NL;

    f32x4 acc[4][2] = {};
    const int wm = (w & 1) * 64, wn = (w >> 1) * 32;
    const int fr = lane & 15, fq = lane >> 4;

    for (int it = 0; it < NL / 128; ++it) {
        const int k0 = it * 128;
        // stage A,B 128x128 as stacked 64-k halves (2048 chunks, 4 passes)
#pragma unroll
        for (int pass = 0; pass < 4; ++pass) {
            const int c = pass * 512 + tid;
            const int kh = c >> 10;              // 0..1 (1024 chunks per half)
            const int r = (c >> 3) & 127;        // row 0..127
            const int jj = (c & 7) ^ (r & 7);    // XOR-swizzled k-chunk
            const int srck = k0 + kh * 64 + jj * 8;
            gload16(Aatt + (size_t)(row0 + r) * NL + srck, (char*)As + c * 16);
            gload16(Bsrc + (size_t)(col0 + r) * NL + srck, (char*)Bs + c * 16);
        }
        __syncthreads();
#pragma unroll
        for (int kh = 0; kh < 2; ++kh)
#pragma unroll
            for (int kt = 0; kt < 2; ++kt) {
                const int hb = kh * 8192;
                const int coff = ((kt * 4 + fq) ^ (fr & 7)) * 8;
                f16x8 af[4], bf[2];
#pragma unroll
                for (int mi = 0; mi < 4; ++mi)
                    af[mi] = *(const f16x8*)&As[hb + (wm + mi * 16 + fr) * 64 + coff];
#pragma unroll
                for (int ni = 0; ni < 2; ++ni)
                    bf[ni] = *(const f16x8*)&Bs[hb + (wn + ni * 16 + fr) * 64 + coff];
#pragma unroll
                for (int mi = 0; mi < 4; ++mi)
#pragma unroll
                    for (int ni = 0; ni < 2; ++ni)
                        acc[mi][ni] = __builtin_amdgcn_mfma_f32_16x16x32_f16(af[mi], bf[ni], acc[mi][ni], 0, 0, 0);
            }
        __syncthreads();
    }
    const size_t ob = (size_t)b * NL * NC;
#pragma unroll
    for (int mi = 0; mi < 4; ++mi) {
        const int gr = row0 + wm + mi * 16 + fq * 4;
#pragma unroll
        for (int ni = 0; ni < 2; ++ni) {
            const int gc = col0 + wn + ni * 16 + fr;
#pragma unroll
            for (int r = 0; r < 4; ++r) {
                const size_t o = ob + (size_t)(gr + r) * NC + gc;
                Out[o] = X[o] + acc[mi][ni][r];
            }
        }
    }
}

extern "C" void kernel_launch(void* const* d_in, const int* in_sizes, int n_in,
                              void* d_out, int out_size, void* d_ws, size_t ws_size,
                              hipStream_t stream)
{
    const float* X  = (const float*)d_in[0];
    const float* Wx = (const float*)d_in[1];
    const float* bx = (const float*)d_in[2];
    const float* Wy = (const float*)d_in[3];
    const float* by = (const float*)d_in[4];
    const float* Wo = (const float*)d_in[5];
    const float* bo = (const float*)d_in[6];
    float* out = (float*)d_out;

    // Workspace (~97 MB): ATT fp16 [0,64MB); Xf16 (16MB) overlaps ATT[0:16MB) —
    // dead (proj done) before score_softmax writes ATT (stream-ordered).
    char* ws = (char*)d_ws;
    u16* ATT = (u16*)ws;
    u16* Xf  = (u16*)ws;
    char* p = ws + 67108864;
    u16* xp  = (u16*)p; p += 8388608;
    u16* yp  = (u16*)p; p += 8388608;
    u16* opT = (u16*)p; p += 16777216;
    u16* WxT = (u16*)p; p += 262144;
    u16* WyT = (u16*)p; p += 262144;
    u16* WoT = (u16*)p; p += 524288;

    cvt_kernel<<<5120, 256, 0, stream>>>(X, Xf, Wx, Wy, Wo, WxT, WyT, WoT);
    proj_kernel<<<dim3(128, 8), 256, 0, stream>>>(Xf, WxT, WyT, WoT, bx, by, bo, xp, yp, opT);
    score_softmax_kernel<<<dim3(32, 32), 512, 0, stream>>>(xp, yp, ATT);
    out_kernel<<<dim3(16, 4, NB), 512, 0, stream>>>(ATT, opT, X, out);
}